// Round 13
// baseline (297.125 us; speedup 1.0000x reference)
//
#include <hip/hip_runtime.h>
#include <hip/hip_bf16.h>

// Problem dims
#define BN 16384
#define FN 256
#define RN 32
#define CN 16
#define H1N 128
#define H2N 32
#define G1N 256
#define G2N 64

typedef __bf16 bf16_t;
typedef __bf16 bf16x8 __attribute__((ext_vector_type(8)));
typedef __bf16 bf16x4 __attribute__((ext_vector_type(4)));
typedef float f32x4 __attribute__((ext_vector_type(4)));
typedef float f32x16 __attribute__((ext_vector_type(16)));

// ---- workspace byte offsets (all 16B-aligned) ----
#define OFF_DATA   0UL
#define OFF_WF1    8388608UL
#define OFF_WF2    8454144UL
#define OFF_WC1    8462336UL
#define OFF_WC2    12656640UL
#define OFF_WC3    13705216UL
#define OFF_FSINI  13770752UL
#define OFF_C3     15867904UL

__device__ __forceinline__ f32x4 mfma16(bf16x8 a, bf16x8 b, f32x4 c) {
  return __builtin_amdgcn_mfma_f32_16x16x32_bf16(a, b, c, 0, 0, 0);
}
__device__ __forceinline__ f32x16 mfma32(bf16x8 a, bf16x8 b, f32x16 c) {
  return __builtin_amdgcn_mfma_f32_32x32x16_bf16(a, b, c, 0, 0, 0);
}

__device__ __forceinline__ float elu_f(float v) {
  float e = __builtin_amdgcn_exp2f(v * 1.44269504f) - 1.0f;
  return v > 0.f ? v : e;
}

// 16-row B-frag from ((row&7)<<4)-swizzled LDS tile (row stride strideB bytes).
__device__ __forceinline__ bf16x8 lfrag(const char* base, int strideB, int n0, int k0, int lane) {
  int row = n0 + (lane & 15);
  int off = (k0 * 2 + ((lane >> 4) << 4)) ^ ((row & 7) << 4);
  return *(const bf16x8*)(base + row * strideB + off);
}

// 32-row B-frag from ((row&15)<<4)-swizzled LDS tile (512B rows).
// Lane l: row = n0 + l%32, k = k0 + 8*(l/32) + e.  32 lanes -> 16 XOR slots -> 2-way (free).
__device__ __forceinline__ bf16x8 lfrag32(const char* base, int strideB, int n0, int k0, int lane) {
  int row = n0 + (lane & 31);
  int off = (k0 * 2 + ((lane >> 5) << 4)) ^ ((row & 15) << 4);
  return *(const bf16x8*)(base + row * strideB + off);
}

// Pack W[(r,)n,k] fp32 -> 16x16x32 fragment order (A or B):
// dst[(((r*KS+ks)*NT+nt)*64+lane)*8+e] = W[r][nt*16+lane%16][ks*32+(lane/16)*8+e]
__device__ __forceinline__ void pack_frag8(const float* __restrict__ src, bf16_t* __restrict__ dst,
                                           int NT, int KS, int g) {
  int per = NT * KS * 64;
  int r = g / per;
  int local = g - r * per;
  int lane = local & 63;
  int fr = local >> 6;
  int ks = fr / NT;
  int nt = fr - ks * NT;
  int N = NT * 16, K = KS * 32;
  int n = nt * 16 + (lane & 15);
  int k = ks * 32 + ((lane >> 4) << 3);
  const float* s = src + (long)r * N * K + (long)n * K + k;
  float4 a = *(const float4*)s;
  float4 b = *(const float4*)(s + 4);
  bf16x8 o;
  o[0] = (bf16_t)a.x; o[1] = (bf16_t)a.y; o[2] = (bf16_t)a.z; o[3] = (bf16_t)a.w;
  o[4] = (bf16_t)b.x; o[5] = (bf16_t)b.y; o[6] = (bf16_t)b.z; o[7] = (bf16_t)b.w;
  *(bf16x8*)(dst + (long)g * 8) = o;
}

// Pack W[(r,)n,k] fp32 -> 32x32x16 A-frag order:
// dst[(((r*KS+ks)*MT+mt)*64+lane)*8+e] = W[r][mt*32+lane%32][ks*16+(lane/32)*8+e]
__device__ __forceinline__ void pack_frag32(const float* __restrict__ src, bf16_t* __restrict__ dst,
                                            int MT, int KS, int g) {
  int per = MT * KS * 64;
  int r = g / per;
  int local = g - r * per;
  int lane = local & 63;
  int fr = local >> 6;
  int ks = fr / MT;
  int mt = fr - ks * MT;
  int N = MT * 32, K = KS * 16;
  int n = mt * 32 + (lane & 31);
  int k = ks * 16 + ((lane >> 5) << 3);
  const float* s = src + (long)r * N * K + (long)n * K + k;
  float4 a = *(const float4*)s;
  float4 b = *(const float4*)(s + 4);
  bf16x8 o;
  o[0] = (bf16_t)a.x; o[1] = (bf16_t)a.y; o[2] = (bf16_t)a.z; o[3] = (bf16_t)a.w;
  o[4] = (bf16_t)b.x; o[5] = (bf16_t)b.y; o[6] = (bf16_t)b.z; o[7] = (bf16_t)b.w;
  *(bf16x8*)(dst + (long)g * 8) = o;
}

#define G_DATA 524288
#define G_WC1  262144
#define G_WC2  65536
#define G_WF1  4096
#define G_WC3  4096
#define G_WF2  512
#define G_TOTAL (G_DATA + G_WC1 + G_WC2 + G_WF1 + G_WC3 + G_WF2)

__global__ __launch_bounds__(256) void k0_pack(
    const float* __restrict__ data, const float* __restrict__ Wf1, const float* __restrict__ Wf2,
    const float* __restrict__ Wc1, const float* __restrict__ Wc2, const float* __restrict__ Wc3,
    char* __restrict__ ws)
{
  int g = blockIdx.x * 256 + threadIdx.x;
  if (g < G_DATA) {
    const float* s = data + (long)g * 8;
    float4 a = *(const float4*)s, b = *(const float4*)(s + 4);
    bf16x8 o;
    o[0] = (bf16_t)a.x; o[1] = (bf16_t)a.y; o[2] = (bf16_t)a.z; o[3] = (bf16_t)a.w;
    o[4] = (bf16_t)b.x; o[5] = (bf16_t)b.y; o[6] = (bf16_t)b.z; o[7] = (bf16_t)b.w;
    *(bf16x8*)((bf16_t*)(ws + OFF_DATA) + (long)g * 8) = o;
    return;
  }
  g -= G_DATA;
  if (g < G_WC1) { pack_frag32(Wc1, (bf16_t*)(ws + OFF_WC1), 8, 16, g); return; }   // 32x32 A-frags
  g -= G_WC1;
  if (g < G_WC2) { pack_frag32(Wc2, (bf16_t*)(ws + OFF_WC2), 2, 16, g); return; }   // 32x32 A-frags
  g -= G_WC2;
  if (g < G_WF1) { pack_frag8(Wf1, (bf16_t*)(ws + OFF_WF1), 8, 8, g); return; }
  g -= G_WF1;
  if (g < G_WC3) { pack_frag8(Wc3, (bf16_t*)(ws + OFF_WC3), 1, 2, g); return; }
  g -= G_WC3;
  if (g < G_WF2) { pack_frag8(Wf2, (bf16_t*)(ws + OFF_WF2), 2, 4, g); return; }
}

// ---------------- K1: FS chain, per (rule, 64-row tile). R11 body, standalone. ----------------
__global__ __launch_bounds__(512) void k1_fs(
    const float* __restrict__ data, const float* __restrict__ proto, const float* __restrict__ var,
    const float* __restrict__ bf1g, const float* __restrict__ bf2g,
    const float* __restrict__ Wf3g, const float* __restrict__ bf3g,
    const bf16_t* __restrict__ Wf1p, const bf16_t* __restrict__ Wf2p,
    float* __restrict__ fsini)
{
  __shared__ __attribute__((aligned(16))) char smem[38912];
  char* fs_lds   = smem;
  bf16_t* h2t    = (bf16_t*)(smem + 32768);
  float* proto_s = (float*)(smem + 36864);
  float* ivar_s  = (float*)(smem + 37888);

  const int bid = blockIdx.x;
  const int r   = bid >> 8;
  const int b0  = (bid & 255) << 6;
  const int tid = threadIdx.x;
  const int lane = tid & 63;
  const int w   = tid >> 6;

  if (tid < FN) {
    proto_s[tid] = proto[r * FN + tid];
    float v = var[r * FN + tid];
    v = fminf(fmaxf(v, 1e-4f), 0.1f);
    ivar_s[tid] = 1.4426950408889634f * 0.5f / (v * v);
  }
  __syncthreads();

  { // membership
    const int row = tid >> 3;
    const int f0  = (tid & 7) << 5;
    const float* dp = data + (long)(b0 + row) * FN + f0;
    char* mrow = fs_lds + row * 512;
    const int sw = (row & 7) << 4;
    #pragma unroll
    for (int i = 0; i < 4; ++i) {
      const int f = f0 + i * 8;
      float4 x0 = *(const float4*)(dp + i * 8);
      float4 x1 = *(const float4*)(dp + i * 8 + 4);
      bf16x8 m; float d;
      d = x0.x - proto_s[f + 0]; m[0] = (bf16_t)__builtin_amdgcn_exp2f(-d * d * ivar_s[f + 0]);
      d = x0.y - proto_s[f + 1]; m[1] = (bf16_t)__builtin_amdgcn_exp2f(-d * d * ivar_s[f + 1]);
      d = x0.z - proto_s[f + 2]; m[2] = (bf16_t)__builtin_amdgcn_exp2f(-d * d * ivar_s[f + 2]);
      d = x0.w - proto_s[f + 3]; m[3] = (bf16_t)__builtin_amdgcn_exp2f(-d * d * ivar_s[f + 3]);
      d = x1.x - proto_s[f + 4]; m[4] = (bf16_t)__builtin_amdgcn_exp2f(-d * d * ivar_s[f + 4]);
      d = x1.y - proto_s[f + 5]; m[5] = (bf16_t)__builtin_amdgcn_exp2f(-d * d * ivar_s[f + 5]);
      d = x1.z - proto_s[f + 6]; m[6] = (bf16_t)__builtin_amdgcn_exp2f(-d * d * ivar_s[f + 6]);
      d = x1.w - proto_s[f + 7]; m[7] = (bf16_t)__builtin_amdgcn_exp2f(-d * d * ivar_s[f + 7]);
      *(bf16x8*)(mrow + ((f * 2) ^ sw)) = m;
    }
  }
  __syncthreads();

  // GEMM1: h1T[128][64] = Wf1 @ memT. wave w -> m-tile w, n-tiles 0..3.
  f32x4 acc[4] = {};
  #pragma unroll
  for (int ks = 0; ks < 8; ++ks) {
    bf16x8 a = *(const bf16x8*)(Wf1p + (((ks * 8 + w) * 64 + lane)) * 8);
    #pragma unroll
    for (int j = 0; j < 4; ++j) {
      bf16x8 bb = lfrag(fs_lds, 512, j * 16, ks * 32, lane);
      acc[j] = mfma16(a, bb, acc[j]);
    }
  }
  __syncthreads();

  {
    const int hb = w * 16 + ((lane >> 4) << 2);
    f32x4 bias = *(const f32x4*)(bf1g + hb);
    #pragma unroll
    for (int j = 0; j < 4; ++j) {
      const int b = j * 16 + (lane & 15);
      bf16x4 o;
      #pragma unroll
      for (int q = 0; q < 4; ++q)
        o[q] = (bf16_t)fmaxf(acc[j][q] + bias[q], 0.f);
      *(bf16x4*)(fs_lds + b * 256 + ((hb * 2) ^ ((b & 7) << 4))) = o;
    }
  }
  __syncthreads();

  // GEMM2: h2T[32][64] = Wf2 @ h1T
  {
    const int m = w >> 2;
    const int n = w & 3;
    f32x4 acc2 = {};
    #pragma unroll
    for (int ks = 0; ks < 4; ++ks) {
      bf16x8 a = *(const bf16x8*)(Wf2p + (((ks * 2 + m) * 64 + lane)) * 8);
      bf16x8 bb = lfrag(fs_lds, 256, n * 16, ks * 32, lane);
      acc2 = mfma16(a, bb, acc2);
    }
    const int p0 = m * 16 + ((lane >> 4) << 2);
    const int b  = n * 16 + (lane & 15);
    f32x4 bias = *(const f32x4*)(bf2g + p0);
    #pragma unroll
    for (int q = 0; q < 4; ++q)
      h2t[(p0 + q) * 64 + b] = (bf16_t)fmaxf(acc2[q] + bias[q], 0.f);
  }
  __syncthreads();

  if (tid < 64) {
    float s = bf3g[0];
    #pragma unroll
    for (int p = 0; p < H2N; ++p) s += (float)h2t[p * 64 + tid] * Wf3g[p];
    fsini[(long)(b0 + tid) * RN + r] = fmaxf(s, 0.f);
  }
}

__global__ __launch_bounds__(256) void k2_softmax(const float* __restrict__ fsini,
                                                  float* __restrict__ fire)
{
  int b = blockIdx.x * 256 + threadIdx.x;
  float v[RN];
  const float4* p = (const float4*)(fsini + (long)b * RN);
  #pragma unroll
  for (int i = 0; i < RN / 4; ++i) {
    float4 t = p[i];
    v[4 * i] = t.x; v[4 * i + 1] = t.y; v[4 * i + 2] = t.z; v[4 * i + 3] = t.w;
  }
  float m = v[0];
  #pragma unroll
  for (int i = 1; i < RN; ++i) m = fmaxf(m, v[i]);
  float s = 0.f;
  #pragma unroll
  for (int i = 0; i < RN; ++i) { v[i] = expf(v[i] - m); s += v[i]; }
  float inv = 1.f / s;
  float4* o = (float4*)(fire + (long)b * RN);
  #pragma unroll
  for (int i = 0; i < RN / 4; ++i) {
    float4 t; t.x = v[4 * i] * inv; t.y = v[4 * i + 1] * inv;
    t.z = v[4 * i + 2] * inv; t.w = v[4 * i + 3] * inv;
    o[i] = t;
  }
}

// ---------------- K3: consequent chain, per (rule, 128-row tile), 32x32x16 MFMA ----------------
// GEMM1/GEMM2 on 32x32x16 (2x op-intensity per operand byte vs 16x16x32).
// a_lds: 128x256 bf16, 512B rows, ((row&15)<<4) XOR swizzle -> 32-lane reads conflict-free.
// 8 waves: GEMM1 wave = 2m x 2n 32-tiles (acc 2x2 f32x16).
__global__ __launch_bounds__(512, 4) void k3_cons(
    const bf16_t* __restrict__ datab,
    const bf16_t* __restrict__ Wc1p, const bf16_t* __restrict__ Wc2p, const bf16_t* __restrict__ Wc3p,
    const float* __restrict__ bc1, const float* __restrict__ bc2, const float* __restrict__ bc3,
    float* __restrict__ c3buf)
{
  __shared__ __attribute__((aligned(16))) char a_lds[65536];   // data then c1T, [128][256] bf16 swz16
  __shared__ __attribute__((aligned(16))) char c2_lds[16384];  // c2T [128][64] bf16 swz8

  // XCD swizzle over 4096 blocks: xcd owns rules 4*xcd..4*xcd+3
  const int bid = blockIdx.x;
  const int xcd = bid & 7;
  const int kk  = bid >> 3;            // 0..511
  const int r   = xcd * 4 + (kk >> 7);
  const int b0  = (kk & 127) << 7;     // 128-row tiles

  const int tid = threadIdx.x;
  const int lane = tid & 63;
  const int w   = tid >> 6;

  { // stage data tile [128][256]: 4 threads/row, 64 elems each
    const int row = tid >> 2;
    const int e0  = (tid & 3) << 6;
    const bf16_t* sp = datab + (long)(b0 + row) * FN + e0;
    char* drow = a_lds + row * 512;
    const int sw = (row & 15) << 4;
    #pragma unroll
    for (int i = 0; i < 8; ++i) {
      bf16x8 v = *(const bf16x8*)(sp + i * 8);
      *(bf16x8*)(drow + (((e0 + i * 8) * 2) ^ sw)) = v;
    }
  }
  __syncthreads();

  // GEMM1: c1T[g1=256][b=128] = Wc1 @ dataT. 8m x 4n 32-tiles; wave: m {2wm,2wm+1}, n {2wn,2wn+1}.
  const int wm = w >> 1;   // 0..3
  const int wn = w & 1;    // 0..1
  const bf16_t* W1 = Wc1p + (long)r * G1N * FN;
  f32x16 acc[2][2] = {};
  #pragma unroll
  for (int ks = 0; ks < 16; ++ks) {
    bf16x8 a[2], bb[2];
    #pragma unroll
    for (int i = 0; i < 2; ++i)
      a[i] = *(const bf16x8*)(W1 + (((ks * 8 + wm * 2 + i) * 64 + lane)) * 8);
    #pragma unroll
    for (int j = 0; j < 2; ++j)
      bb[j] = lfrag32(a_lds, 512, (wn * 2 + j) * 32, ks * 16, lane);
    #pragma unroll
    for (int i = 0; i < 2; ++i)
      #pragma unroll
      for (int j = 0; j < 2; ++j)
        acc[i][j] = mfma32(a[i], bb[j], acc[i][j]);
  }
  __syncthreads();  // data tile dead

  // c1T epilogue: elu -> bf16 [b][g1] overlay. 32x32 C/D: col b = lane%32,
  // row g1 = m0 + grp*8 + 4*(lane/32) + q  (reg = grp*4+q).
  #pragma unroll
  for (int i = 0; i < 2; ++i) {
    const int m0 = (wm * 2 + i) * 32;
    #pragma unroll
    for (int j = 0; j < 2; ++j) {
      const int b = (wn * 2 + j) * 32 + (lane & 31);
      char* brow = a_lds + b * 512;
      const int sw = (b & 15) << 4;
      #pragma unroll
      for (int grp = 0; grp < 4; ++grp) {
        const int g1 = m0 + grp * 8 + ((lane >> 5) << 2);
        f32x4 bias = *(const f32x4*)(bc1 + r * G1N + g1);
        bf16x4 o;
        #pragma unroll
        for (int q = 0; q < 4; ++q)
          o[q] = (bf16_t)elu_f(acc[i][j][grp * 4 + q] + bias[q]);
        *(bf16x4*)(brow + ((g1 * 2) ^ sw)) = o;
      }
    }
  }
  __syncthreads();

  // GEMM2: c2T[g2=64][b=128] = Wc2 @ c1T. 2m x 4n 32-tiles; wave: m = w>>2, n = w&3.
  const int m2 = w >> 2;   // 0..1
  const int n2 = w & 3;    // 0..3
  const bf16_t* W2 = Wc2p + (long)r * G2N * G1N;
  f32x16 acc2 = {};
  #pragma unroll
  for (int ks = 0; ks < 16; ++ks) {
    bf16x8 a = *(const bf16x8*)(W2 + (((ks * 2 + m2) * 64 + lane)) * 8);
    bf16x8 bb = lfrag32(a_lds, 512, n2 * 32, ks * 16, lane);
    acc2 = mfma32(a, bb, acc2);
  }
  {
    const int m0 = m2 * 32;
    const int b = n2 * 32 + (lane & 31);
    char* brow = c2_lds + b * 128;
    const int sw = (b & 7) << 4;
    #pragma unroll
    for (int grp = 0; grp < 4; ++grp) {
      const int g2 = m0 + grp * 8 + ((lane >> 5) << 2);
      f32x4 bias = *(const f32x4*)(bc2 + r * G2N + g2);
      bf16x4 o;
      #pragma unroll
      for (int q = 0; q < 4; ++q)
        o[q] = (bf16_t)elu_f(acc2[grp * 4 + q] + bias[q]);
      *(bf16x4*)(brow + ((g2 * 2) ^ sw)) = o;
    }
  }
  __syncthreads();

  // GEMM3: c3T[c=16][b=128], 16x16x32, K=64. 8 n-tiles of 16, one per wave.
  {
    const bf16_t* W3 = Wc3p + (long)r * CN * G2N;
    f32x4 acc3 = {};
    #pragma unroll
    for (int ks = 0; ks < 2; ++ks) {
      bf16x8 a = *(const bf16x8*)(W3 + (((long)ks * 64 + lane)) * 8);
      bf16x8 bb = lfrag(c2_lds, 128, w * 16, ks * 32, lane);
      acc3 = mfma16(a, bb, acc3);
    }
    const int c0 = ((lane >> 4) << 2);
    const int b  = w * 16 + (lane & 15);
    f32x4 bias = *(const f32x4*)(bc3 + r * CN + c0);
    f32x4 o;
    #pragma unroll
    for (int q = 0; q < 4; ++q) o[q] = fmaxf(acc3[q] + bias[q], 0.f);
    *(f32x4*)(c3buf + ((long)r * BN + b0 + b) * CN + c0) = o;
  }
}

__global__ __launch_bounds__(256) void k4_out(const float* __restrict__ c3buf,
                                              const float* __restrict__ fire,
                                              float* __restrict__ out)
{
  int t = blockIdx.x * 256 + threadIdx.x;
  int b = t >> 2, c4 = (t & 3) << 2;
  const float* fp = fire + (long)b * RN;
  f32x4 s = {};
  #pragma unroll
  for (int rr = 0; rr < RN; ++rr) {
    float fw = fp[rr];
    f32x4 v = *(const f32x4*)(c3buf + ((long)rr * BN + b) * CN + c4);
    s += fw * v;
  }
  *(f32x4*)(out + (long)b * CN + c4) = s;
}

extern "C" void kernel_launch(void* const* d_in, const int* in_sizes, int n_in,
                              void* d_out, int out_size, void* d_ws, size_t ws_size,
                              hipStream_t stream) {
  const float* data = (const float*)d_in[0];
  const float* proto = (const float*)d_in[1];
  const float* var  = (const float*)d_in[2];
  const float* Wf1  = (const float*)d_in[3];
  const float* bf1  = (const float*)d_in[4];
  const float* Wf2  = (const float*)d_in[5];
  const float* bf2  = (const float*)d_in[6];
  const float* Wf3  = (const float*)d_in[7];
  const float* bf3  = (const float*)d_in[8];
  const float* Wc1  = (const float*)d_in[9];
  const float* bc1  = (const float*)d_in[10];
  const float* Wc2  = (const float*)d_in[11];
  const float* bc2  = (const float*)d_in[12];
  const float* Wc3  = (const float*)d_in[13];
  const float* bc3  = (const float*)d_in[14];

  char* ws = (char*)d_ws;
  bf16_t* datab = (bf16_t*)(ws + OFF_DATA);
  bf16_t* Wf1p  = (bf16_t*)(ws + OFF_WF1);
  bf16_t* Wf2p  = (bf16_t*)(ws + OFF_WF2);
  bf16_t* Wc1p  = (bf16_t*)(ws + OFF_WC1);
  bf16_t* Wc2p  = (bf16_t*)(ws + OFF_WC2);
  bf16_t* Wc3p  = (bf16_t*)(ws + OFF_WC3);
  float*  fsini = (float*)(ws + OFF_FSINI);
  float*  c3buf = (float*)(ws + OFF_C3);

  float* out  = (float*)d_out;               // [B][C]
  float* fire = out + (long)BN * CN;         // [B][R]

  k0_pack<<<G_TOTAL / 256, 256, 0, stream>>>(data, Wf1, Wf2, Wc1, Wc2, Wc3, ws);
  k3_cons<<<RN * (BN / 128), 512, 0, stream>>>(datab, Wc1p, Wc2p, Wc3p, bc1, bc2, bc3, c3buf);
  k1_fs<<<RN * (BN / 64), 512, 0, stream>>>(data, proto, var, bf1, bf2, Wf3, bf3,
                                            Wf1p, Wf2p, fsini);
  k2_softmax<<<BN / 256, 256, 0, stream>>>(fsini, fire);
  k4_out<<<(BN * CN / 4) / 256, 256, 0, stream>>>(c3buf, fire, out);
}